// Round 3
// baseline (610.897 us; speedup 1.0000x reference)
//
#include <hip/hip_runtime.h>

// SigmoidLoss: loss_ij = t_ij * log(clip(sigmoid(x_ij), eps, 1-eps));
// per row: max over positive labels, negate, weight; then mean over rows.
// log∘clip∘sigmoid is monotone => masked max over x commutes with the
// transform: find max x over positives, transform once per row.
// Pure streaming masked-max reduction => memory-bound (655 MB, one pass).
//
// R8: R5(565)≈R7(573) despite opposite MLP/occupancy choices, R6 spill
// regression aside => kernel is insensitive to in-flight count (Little's law:
// ~64+ wave-loads/CU vs ~20 needed). Limiter = request efficiency, not TLP.
// Row-per-wave mapping is structurally misaligned: row base = row*20000 B,
// 20000 mod 128 = 32 => every 1KB wave-load spans 9 lines instead of 8, and
// NT (evict-first) loads likely re-fetch the shared boundary lines.
// Fix: flat slab mapping. 16384*1250 vec4 = 2048 blocks x 10000 vec4, and
// 10000 vec4 = EXACTLY 8 rows/block. Slab byte base = b*160000 = b*625*256
// => 256B-aligned; every wave-load is 128B-line-aligned => zero overfetch.
//  - j loop fully unrolled; per-j row index is COMPILE-TIME (each 256-chunk
//    window spans <=1 row boundary; boundary j's do two constant-index
//    predicated updates) => m[8] stays in registers (rule #20)
//  - plain loads (drop NT): restores normal caching; data is read-once
//  - one __syncthreads at kernel end for the 8-row block reduction

#define NROWS 16384
#define NCOLS 5000
#define NVEC_ROW 1250          // vec4 per row
#define VEC_PER_BLOCK 10000    // = 8 rows, exact
#define ROWS_PER_BLOCK 8
#define NBLOCKS 2048
#define EPSF  1e-6f
#define NEGF  -3.0e38f

typedef float fvec4 __attribute__((ext_vector_type(4)));
typedef int   ivec4 __attribute__((ext_vector_type(4)));

__global__ __launch_bounds__(256, 4) void row_loss_kernel(
    const float* __restrict__ inp,
    const int*   __restrict__ tgt,
    const float* __restrict__ w,
    float*       __restrict__ row_loss)
{
    const int tid  = threadIdx.x;
    const int lane = tid & 63;
    const int wid  = tid >> 6;

    const size_t vbase = (size_t)blockIdx.x * VEC_PER_BLOCK;
    const fvec4* __restrict__ x4 = (const fvec4*)inp + vbase;
    const ivec4* __restrict__ t4 = (const ivec4*)tgt + vbase;

    float m[ROWS_PER_BLOCK];
    #pragma unroll
    for (int r = 0; r < ROWS_PER_BLOCK; ++r) m[r] = NEGF;

    // 10000 = 39*256 + 16. j fully unrolled => all row indices compile-time.
    #pragma unroll
    for (int j = 0; j < 39; ++j) {
        const int l = j * 256 + tid;          // [j*256, j*256+255]
        const fvec4 xv = x4[l];
        const ivec4 tv = t4[l];
        const float mv = fmaxf(
            fmaxf((tv[0] > 0) ? xv[0] : NEGF, (tv[1] > 0) ? xv[1] : NEGF),
            fmaxf((tv[2] > 0) ? xv[2] : NEGF, (tv[3] > 0) ? xv[3] : NEGF));
        const int c0 = (j * 256) / NVEC_ROW;          // compile-time
        const int c1 = (j * 256 + 255) / NVEC_ROW;    // compile-time
        if (c0 == c1) {
            m[c0] = fmaxf(m[c0], mv);
        } else {
            // window spans one row boundary at l == c1*NVEC_ROW
            const bool in0 = l < c1 * NVEC_ROW;
            m[c0] = fmaxf(m[c0], in0 ? mv : NEGF);
            m[c1] = fmaxf(m[c1], in0 ? NEGF : mv);
        }
    }
    // tail: l = 9984 + tid for tid < 16; 9984/1250 == 9999/1250 == 7
    if (tid < 16) {
        const int l = 39 * 256 + tid;
        const fvec4 xv = x4[l];
        const ivec4 tv = t4[l];
        const float mv = fmaxf(
            fmaxf((tv[0] > 0) ? xv[0] : NEGF, (tv[1] > 0) ? xv[1] : NEGF),
            fmaxf((tv[2] > 0) ? xv[2] : NEGF, (tv[3] > 0) ? xv[3] : NEGF));
        m[7] = fmaxf(m[7], mv);
    }

    // per-wave reduction of all 8 row-maxes (register-only), then cross-wave
    #pragma unroll
    for (int r = 0; r < ROWS_PER_BLOCK; ++r) {
        float v = m[r];
        #pragma unroll
        for (int off = 32; off > 0; off >>= 1)
            v = fmaxf(v, __shfl_xor(v, off, 64));
        m[r] = v;
    }

    __shared__ float sm[ROWS_PER_BLOCK][4];
    if (lane == 0) {
        #pragma unroll
        for (int r = 0; r < ROWS_PER_BLOCK; ++r) sm[r][wid] = m[r];
    }
    __syncthreads();

    // threads 0..7: finalize row r
    if (tid < ROWS_PER_BLOCK) {
        const int r = tid;
        const float mx = fmaxf(fmaxf(sm[r][0], sm[r][1]),
                               fmaxf(sm[r][2], sm[r][3]));
        const int row = blockIdx.x * ROWS_PER_BLOCK + r;
        float loss = 0.0f;
        if (mx > -1.0e38f) {   // row has at least one positive
            float p = 1.0f / (1.0f + __expf(-mx));
            p = fminf(fmaxf(p, EPSF), 1.0f - EPSF);
            loss = -logf(p) * w[row];
        }
        row_loss[row] = loss;  // every row written => no ws pre-zero needed
    }
}

__global__ __launch_bounds__(1024) void reduce_mean_kernel(
    const float* __restrict__ row_loss,
    float*       __restrict__ out)
{
    // 16384 floats = 4096 float4; 1024 threads x FOUR float4 each.
    const fvec4* __restrict__ rl4 = (const fvec4*)row_loss;
    float s = 0.0f;
    #pragma unroll
    for (int j = 0; j < 4; ++j) {
        fvec4 v = rl4[threadIdx.x + j * 1024];
        s += (v[0] + v[1]) + (v[2] + v[3]);
    }

    #pragma unroll
    for (int off = 32; off > 0; off >>= 1)
        s += __shfl_xor(s, off, 64);

    __shared__ float ssum[16];
    const int lane = threadIdx.x & 63;
    const int wid  = threadIdx.x >> 6;
    if (lane == 0) ssum[wid] = s;
    __syncthreads();

    if (threadIdx.x == 0) {
        float tot = 0.0f;
        #pragma unroll
        for (int i = 0; i < 16; ++i) tot += ssum[i];
        out[0] = tot / (float)NROWS;
    }
}

extern "C" void kernel_launch(void* const* d_in, const int* in_sizes, int n_in,
                              void* d_out, int out_size, void* d_ws, size_t ws_size,
                              hipStream_t stream) {
    const float* inp = (const float*)d_in[0];
    const int*   tgt = (const int*)d_in[1];
    const float* w   = (const float*)d_in[2];
    float* row_loss  = (float*)d_ws;          // 16384 floats = 64 KB scratch
    float* out       = (float*)d_out;

    row_loss_kernel<<<NBLOCKS, 256, 0, stream>>>(inp, tgt, w, row_loss);
    reduce_mean_kernel<<<1, 1024, 0, stream>>>(row_loss, out);
}

// Round 4
// 570.357 us; speedup vs baseline: 1.0711x; 1.0711x over previous
//
#include <hip/hip_runtime.h>

// SigmoidLoss: loss_ij = t_ij * log(clip(sigmoid(x_ij), eps, 1-eps));
// per row: max over positive labels, negate, weight; then mean over rows.
// log∘clip∘sigmoid is monotone => masked max over x commutes with the
// transform: find max x over positives, transform once per row.
// Pure streaming masked-max reduction => memory-bound (655 MB, one pass).
//
// R9: R8 (slab-aligned + plain loads + 39-deep full unroll) regressed — but
// it changed three things at once. This round isolates ALIGNMENT on top of
// the proven R7 structure (wave-per-row, NT loads, unroll-1 4-chunk bursts).
// Defect being fixed: row byte base = row*20000, 20000 mod 128 = 32 => every
// 1KB wave-load spans 9 cache lines; with NT (no-allocate) loads the shared
// boundary line is re-fetched from HBM by the neighboring chunk (~+12.5%
// HBM traffic + TA line-split overhead on every load).
// Fix: per-row head shift h = (128 - 32*(row&3)) & 127 bytes; the 19 main
// chunks then start 128B-aligned. Head (<=6 vec4) and tail (<=34 vec4) are
// two predicated loads folded into the peeled final group.

#define NROWS 16384
#define NCOLS 5000
#define NVEC  (NCOLS / 4)   // 1250 vec4 per row
#define EPSF  1e-6f
#define NEGF  -3.0e38f

typedef float fvec4 __attribute__((ext_vector_type(4)));
typedef int   ivec4 __attribute__((ext_vector_type(4)));

__global__ __launch_bounds__(256, 8) void row_loss_kernel(
    const float* __restrict__ inp,
    const int*   __restrict__ tgt,
    const float* __restrict__ w,
    float*       __restrict__ row_loss)
{
    const int lane = threadIdx.x & 63;
    const int wid  = threadIdx.x >> 6;
    const int row  = blockIdx.x * 4 + wid;          // [0, 16384), exact cover

    const char* __restrict__ xrow = (const char*)(inp + (size_t)row * NCOLS);
    const char* __restrict__ trow = (const char*)(tgt + (size_t)row * NCOLS);

    // row base mod 128 = 32*(row&3); shift so main chunks are line-aligned
    const int hb = (128 - ((row & 3) << 5)) & 127;  // head bytes: {0,96,64,32}
    const int hv = hb >> 4;                         // head vec4s: {0,6,4,2}

    // steady-state per-lane pointers: lane0 at xrow + hb (128B-aligned)
    const char* xb = xrow + hb + lane * 16;
    const char* tb = trow + hb + lane * 16;

    float m0 = NEGF, m1 = NEGF, m2 = NEGF, m3 = NEGF;

    // aligned region: 19 chunks of 64 vec4 = 1216 vec4 at [hv, hv+1216)
    // groups 0..3 cover chunks 0..15; peeled final group covers 16..18 +
    // predicated chunk 19 (tail, 34-hv vec4) + predicated head (hv vec4).
    #pragma unroll 1
    for (int g = 0; g < 4; ++g) {
        fvec4 xv[4];
        ivec4 tv[4];
        #pragma unroll
        for (int k = 0; k < 4; ++k)
            xv[k] = __builtin_nontemporal_load((const fvec4*)(xb + k * 1024));
        #pragma unroll
        for (int k = 0; k < 4; ++k)
            tv[k] = __builtin_nontemporal_load((const ivec4*)(tb + k * 1024));
        #pragma unroll
        for (int k = 0; k < 4; ++k) {
            m0 = fmaxf(m0, (tv[k][0] > 0) ? xv[k][0] : NEGF);
            m1 = fmaxf(m1, (tv[k][1] > 0) ? xv[k][1] : NEGF);
            m2 = fmaxf(m2, (tv[k][2] > 0) ? xv[k][2] : NEGF);
            m3 = fmaxf(m3, (tv[k][3] > 0) ? xv[k][3] : NEGF);
        }
        xb += 4096;
        tb += 4096;
    }

    // final: chunks 16..18 full, chunk 19 tail (lane < 34-hv), head (lane < hv)
    {
        fvec4 xv[5];
        ivec4 tv[5];
        #pragma unroll
        for (int k = 0; k < 3; ++k)
            xv[k] = __builtin_nontemporal_load((const fvec4*)(xb + k * 1024));
        #pragma unroll
        for (int k = 0; k < 3; ++k)
            tv[k] = __builtin_nontemporal_load((const ivec4*)(tb + k * 1024));
        if (lane < 34 - hv) {   // tail: vec idx hv+1216+lane < 1250
            xv[3] = __builtin_nontemporal_load((const fvec4*)(xb + 3 * 1024));
            tv[3] = __builtin_nontemporal_load((const ivec4*)(tb + 3 * 1024));
        } else {
            xv[3] = (fvec4)0.0f;
            tv[3] = (ivec4)0;                      // t==0 => contributes NEGF
        }
        if (lane < hv) {        // head: vec idx = lane < hv
            xv[4] = __builtin_nontemporal_load((const fvec4*)(xrow + lane * 16));
            tv[4] = __builtin_nontemporal_load((const ivec4*)(trow + lane * 16));
        } else {
            xv[4] = (fvec4)0.0f;
            tv[4] = (ivec4)0;
        }
        #pragma unroll
        for (int k = 0; k < 5; ++k) {
            m0 = fmaxf(m0, (tv[k][0] > 0) ? xv[k][0] : NEGF);
            m1 = fmaxf(m1, (tv[k][1] > 0) ? xv[k][1] : NEGF);
            m2 = fmaxf(m2, (tv[k][2] > 0) ? xv[k][2] : NEGF);
            m3 = fmaxf(m3, (tv[k][3] > 0) ? xv[k][3] : NEGF);
        }
    }

    float m = fmaxf(fmaxf(m0, m1), fmaxf(m2, m3));

    // wave (64-lane) max reduction — register-only, no LDS, no barrier
    #pragma unroll
    for (int off = 32; off > 0; off >>= 1)
        m = fmaxf(m, __shfl_xor(m, off, 64));

    if (lane == 0) {
        float loss = 0.0f;
        if (m > -1.0e38f) {  // row has at least one positive
            float p = 1.0f / (1.0f + __expf(-m));
            p = fminf(fmaxf(p, EPSF), 1.0f - EPSF);
            loss = -logf(p) * w[row];
        }
        row_loss[row] = loss;  // every row written => no ws pre-zero needed
    }
}

__global__ __launch_bounds__(1024) void reduce_mean_kernel(
    const float* __restrict__ row_loss,
    float*       __restrict__ out)
{
    // 16384 floats = 4096 float4; 1024 threads x FOUR float4 each.
    const fvec4* __restrict__ rl4 = (const fvec4*)row_loss;
    float s = 0.0f;
    #pragma unroll
    for (int j = 0; j < 4; ++j) {
        fvec4 v = rl4[threadIdx.x + j * 1024];
        s += (v[0] + v[1]) + (v[2] + v[3]);
    }

    #pragma unroll
    for (int off = 32; off > 0; off >>= 1)
        s += __shfl_xor(s, off, 64);

    __shared__ float ssum[16];
    const int lane = threadIdx.x & 63;
    const int wid  = threadIdx.x >> 6;
    if (lane == 0) ssum[wid] = s;
    __syncthreads();

    if (threadIdx.x == 0) {
        float tot = 0.0f;
        #pragma unroll
        for (int i = 0; i < 16; ++i) tot += ssum[i];
        out[0] = tot / (float)NROWS;
    }
}

extern "C" void kernel_launch(void* const* d_in, const int* in_sizes, int n_in,
                              void* d_out, int out_size, void* d_ws, size_t ws_size,
                              hipStream_t stream) {
    const float* inp = (const float*)d_in[0];
    const int*   tgt = (const int*)d_in[1];
    const float* w   = (const float*)d_in[2];
    float* row_loss  = (float*)d_ws;          // 16384 floats = 64 KB scratch
    float* out       = (float*)d_out;

    row_loss_kernel<<<4096, 256, 0, stream>>>(inp, tgt, w, row_loss);
    reduce_mean_kernel<<<1, 1024, 0, stream>>>(row_loss, out);
}